// Round 1
// baseline (292.706 us; speedup 1.0000x reference)
//
#include <hip/hip_runtime.h>
#include <stdint.h>

#define B_ 8
#define N_ 2048
#define D_ 128

typedef unsigned short u16;
typedef unsigned int u32;
using f32x4 = __attribute__((ext_vector_type(4))) float;
using bf16x8 = __attribute__((ext_vector_type(8))) short;
using u16x8 = __attribute__((ext_vector_type(8))) u16;

// RNE float -> bf16 bits (inputs are finite; no NaN handling needed)
__device__ inline u16 f2bf(float x) {
  u32 u = __float_as_uint(x);
  u32 r = (u + 0x7FFFu + ((u >> 16) & 1u)) >> 16;
  return (u16)r;
}

// ---------------------------------------------------------------------------
// Prep: E[b][i][d] (fp32) -> ET[b][d][i] (bf16, linear layout)
// ---------------------------------------------------------------------------
__global__ __launch_bounds__(256) void prep_et_kernel(const float* __restrict__ E,
                                                      u16* __restrict__ ET) {
  __shared__ float Els[64][132];  // 132 stride: column reads step 4 banks
  const int blk = blockIdx.x;
  const int b = blk >> 5;
  const int i0 = (blk & 31) * 64;
  const int t = threadIdx.x;
  const float* Eb = E + ((size_t)b * N_ + i0) * D_;
#pragma unroll
  for (int s = 0; s < 8; ++s) {
    const int r = (t >> 5) + 8 * s;
    const int c = t & 31;
    f32x4 v = *(const f32x4*)(Eb + r * D_ + c * 4);
#pragma unroll
    for (int e = 0; e < 4; ++e) Els[r][c * 4 + e] = v[e];
  }
  __syncthreads();
  u16* ETb = ET + (size_t)b * D_ * N_;
#pragma unroll
  for (int s = 0; s < 4; ++s) {
    const int d = (t >> 3) + 32 * s;
    const int g = t & 7;
    u16x8 pk;
#pragma unroll
    for (int e = 0; e < 8; ++e) pk[e] = f2bf(Els[g * 8 + e][d]);
    *(u16x8*)(ETb + (size_t)d * N_ + i0 + g * 8) = pk;  // 128B per row-chunk, coalesced
  }
}

// ---------------------------------------------------------------------------
// Main: S[ks][b][j][d] = sum_{i in ks-half} C[b][i][j] * E[b][i][d]  (bf16 MFMA)
// fused: deg[b][i] += nonzero count of C[b][i][j0:j0+64]  (atomics)
// grid 512 = b(8) x jtile(32) x ksplit(2), 256 threads (4 waves, 2x2)
// ---------------------------------------------------------------------------
__global__ __launch_bounds__(256) void gemm_kernel(const float* __restrict__ C,
                                                   const u16* __restrict__ ET,
                                                   float* __restrict__ S,
                                                   int* __restrict__ deg) {
  // swizzled [j][k] / [d][k] bf16 tiles: elem = row*64 + (k ^ (SWZ(row)<<3)),
  // SWZ(r) = (r ^ (r>>3)) & 7  -> conflict-free ds_read_b128 frag reads
  __shared__ __align__(16) u16 Asw[64 * 64];
  __shared__ __align__(16) u16 Bsw[128 * 64];
  const int bid = blockIdx.x;
  const int ks = bid & 1;
  const int jt = (bid >> 1) & 31;
  const int b = bid >> 6;
  const int j0 = jt * 64;
  const int t = threadIdx.x;
  const int lane = t & 63;
  const int wave = t >> 6;
  const int wm = wave >> 1, wn = wave & 1;
  const int lm = lane & 15, lh = lane >> 4;

  const float* Cb = C + (size_t)b * N_ * N_;
  const u16* ETb = ET + (size_t)b * D_ * N_;
  float* Sb = S + (size_t)ks * ((size_t)B_ * N_ * D_) + ((size_t)b * N_ + j0) * D_;
  int* degb = deg + b * N_;

  f32x4 acc[2][4];
#pragma unroll
  for (int i = 0; i < 2; ++i)
#pragma unroll
    for (int j = 0; j < 4; ++j) acc[i][j] = (f32x4)0.0f;

  for (int kt = 0; kt < 16; ++kt) {
    const int i0 = ks * (N_ / 2) + kt * 64;
    // ---- stage B (E^T slice), reg-staged with swizzled b128 writes
#pragma unroll
    for (int s = 0; s < 4; ++s) {
      const int d = (t >> 3) + 32 * s;
      const int g = t & 7;
      u16x8 v = *(const u16x8*)(ETb + (size_t)d * N_ + i0 + g * 8);
      const int swz = (d ^ (d >> 3)) & 7;
      *(u16x8*)&Bsw[d * 64 + ((g ^ swz) << 3)] = v;
    }
    // ---- stage A (C tile, fp32->bf16 transpose) + fused degree count
#pragma unroll
    for (int s = 0; s < 4; ++s) {
      const int i = (t >> 4) + 16 * s;  // k-row within tile
      const int c = t & 15;             // float4 chunk of 4 j's
      f32x4 v = *(const f32x4*)(Cb + (size_t)(i0 + i) * N_ + (j0 + c * 4));
      int cnt = (v[0] != 0.0f) + (v[1] != 0.0f) + (v[2] != 0.0f) + (v[3] != 0.0f);
      cnt += __shfl_xor(cnt, 1);
      cnt += __shfl_xor(cnt, 2);
      cnt += __shfl_xor(cnt, 4);
      cnt += __shfl_xor(cnt, 8);
      if ((lane & 15) == 0) atomicAdd(&degb[i0 + i], cnt);
#pragma unroll
      for (int e = 0; e < 4; ++e) {
        const int jl = c * 4 + e;
        const int swz = (jl ^ (jl >> 3)) & 7;
        Asw[jl * 64 + (i ^ (swz << 3))] = f2bf(v[e]);
      }
    }
    __syncthreads();
    // ---- fragments + MFMA
    bf16x8 af[2][2], bfr[4][2];
#pragma unroll
    for (int fm = 0; fm < 2; ++fm) {
      const int jl = wm * 32 + fm * 16 + lm;
      const int swz = (jl ^ (jl >> 3)) & 7;
#pragma unroll
      for (int kf = 0; kf < 2; ++kf) {
        const int K8 = kf * 32 + lh * 8;
        af[fm][kf] = *(const bf16x8*)&Asw[jl * 64 + (K8 ^ (swz << 3))];
      }
    }
#pragma unroll
    for (int fn = 0; fn < 4; ++fn) {
      const int nl = wn * 64 + fn * 16 + lm;
      const int swz = (nl ^ (nl >> 3)) & 7;
#pragma unroll
      for (int kf = 0; kf < 2; ++kf) {
        const int K8 = kf * 32 + lh * 8;
        bfr[fn][kf] = *(const bf16x8*)&Bsw[nl * 64 + (K8 ^ (swz << 3))];
      }
    }
#pragma unroll
    for (int kf = 0; kf < 2; ++kf)
#pragma unroll
      for (int fm = 0; fm < 2; ++fm)
#pragma unroll
        for (int fn = 0; fn < 4; ++fn)
          acc[fm][fn] = __builtin_amdgcn_mfma_f32_16x16x32_bf16(
              af[fm][kf], bfr[fn][kf], acc[fm][fn], 0, 0, 0);
    __syncthreads();
  }
  // ---- store partial S (fp32); C/D layout: col=lane&15, row=(lane>>4)*4+r
#pragma unroll
  for (int fm = 0; fm < 2; ++fm)
#pragma unroll
    for (int fn = 0; fn < 4; ++fn)
#pragma unroll
      for (int r = 0; r < 4; ++r) {
        const int row = wm * 32 + fm * 16 + lh * 4 + r;
        const int col = wn * 64 + fn * 16 + lm;
        Sb[(size_t)row * D_ + col] = acc[fm][fn][r];
      }
}

// ---------------------------------------------------------------------------
// Final: out[row][d] = relu( sum_f E[row][f]*W[d][f]
//                          + sum_f ((S0+S1)[row][f]/deg[row])*W[d][128+f] + b[d] )
// 256 blocks x 128 thr; 64 rows/block; 8x8 register tile; fp32 VALU
// ---------------------------------------------------------------------------
__global__ __launch_bounds__(128) void out_kernel(const float* __restrict__ E,
                                                  const float* __restrict__ S0,
                                                  const float* __restrict__ S1,
                                                  const int* __restrict__ deg,
                                                  const float* __restrict__ W,
                                                  const float* __restrict__ bias,
                                                  float* __restrict__ out) {
  __shared__ float Wt[64][132];  // Wt[f][d], stride 132: 16B-aligned rows
  __shared__ float Ct[64][76];   // Ct[f][r], stride 76: 16B-aligned rows
  __shared__ float idg[64];
  const int blk = blockIdx.x;
  const int r0 = blk * 64;
  const int t = threadIdx.x;
  if (t < 64) idg[t] = 1.0f / (float)deg[r0 + t];
  float acc[8][8];
#pragma unroll
  for (int i = 0; i < 8; ++i)
#pragma unroll
    for (int j = 0; j < 8; ++j) acc[i][j] = 0.0f;
  const int rg = t >> 4;  // 0..7 -> rows rg*8..rg*8+7
  const int dg = t & 15;  // 0..15 -> cols dg*8..dg*8+7
  __syncthreads();
  for (int fc = 0; fc < 4; ++fc) {
    const int f0 = fc * 64;
    // stage Wt[f][d] = W[d][f0+f]
#pragma unroll
    for (int s = 0; s < 16; ++s) {
      const int d = (t >> 4) + 8 * s;
      const int fq = t & 15;
      f32x4 v = *(const f32x4*)(W + d * 256 + f0 + fq * 4);
#pragma unroll
      for (int e = 0; e < 4; ++e) Wt[fq * 4 + e][d] = v[e];
    }
    // stage Ct[f][r]
    if (fc < 2) {
#pragma unroll
      for (int s = 0; s < 8; ++s) {
        const int r = (t >> 4) + 8 * s;
        const int fq = t & 15;
        f32x4 v = *(const f32x4*)(E + (size_t)(r0 + r) * D_ + f0 + fq * 4);
#pragma unroll
        for (int e = 0; e < 4; ++e) Ct[fq * 4 + e][r] = v[e];
      }
    } else {
      const int fs0 = (fc - 2) * 64;
#pragma unroll
      for (int s = 0; s < 8; ++s) {
        const int r = (t >> 4) + 8 * s;
        const int fq = t & 15;
        const size_t off = (size_t)(r0 + r) * D_ + fs0 + fq * 4;
        f32x4 v0 = *(const f32x4*)(S0 + off);
        f32x4 v1 = *(const f32x4*)(S1 + off);
        const float sc = idg[r];
#pragma unroll
        for (int e = 0; e < 4; ++e) Ct[fq * 4 + e][r] = (v0[e] + v1[e]) * sc;
      }
    }
    __syncthreads();
#pragma unroll 2
    for (int f = 0; f < 64; ++f) {
      f32x4 c0 = *(const f32x4*)&Ct[f][rg * 8];
      f32x4 c1 = *(const f32x4*)&Ct[f][rg * 8 + 4];
      f32x4 w0 = *(const f32x4*)&Wt[f][dg * 8];
      f32x4 w1 = *(const f32x4*)&Wt[f][dg * 8 + 4];
      float cv[8] = {c0[0], c0[1], c0[2], c0[3], c1[0], c1[1], c1[2], c1[3]};
      float wv[8] = {w0[0], w0[1], w0[2], w0[3], w1[0], w1[1], w1[2], w1[3]};
#pragma unroll
      for (int ri = 0; ri < 8; ++ri)
#pragma unroll
        for (int di = 0; di < 8; ++di) acc[ri][di] += cv[ri] * wv[di];
    }
    __syncthreads();
  }
#pragma unroll
  for (int ri = 0; ri < 8; ++ri) {
    const int row = r0 + rg * 8 + ri;
#pragma unroll
    for (int di = 0; di < 8; ++di) {
      const int d = dg * 8 + di;
      float x = acc[ri][di] + bias[d];
      out[(size_t)row * D_ + d] = x > 0.0f ? x : 0.0f;
    }
  }
}

extern "C" void kernel_launch(void* const* d_in, const int* in_sizes, int n_in,
                              void* d_out, int out_size, void* d_ws, size_t ws_size,
                              hipStream_t stream) {
  (void)in_sizes; (void)n_in; (void)out_size; (void)ws_size;
  const float* E = (const float*)d_in[0];
  const float* C = (const float*)d_in[1];
  const float* W = (const float*)d_in[2];
  const float* bias = (const float*)d_in[3];
  float* out = (float*)d_out;

  // workspace layout: deg[8*2048] int | ET bf16 [8][128][2048] | S0 fp32 | S1 fp32
  int* deg = (int*)d_ws;
  u16* ET = (u16*)((char*)d_ws + 65536);
  float* S0 = (float*)((char*)d_ws + 65536 + 4194304);
  float* S1 = S0 + (size_t)B_ * N_ * D_;

  hipMemsetAsync(deg, 0, B_ * N_ * sizeof(int), stream);
  hipLaunchKernelGGL(prep_et_kernel, dim3(256), dim3(256), 0, stream, E, ET);
  hipLaunchKernelGGL(gemm_kernel, dim3(512), dim3(256), 0, stream, C, ET, S0, deg);
  hipLaunchKernelGGL(out_kernel, dim3(256), dim3(128), 0, stream, E, S0, S1, deg, W, bias, out);
}

// Round 2
// 230.640 us; speedup vs baseline: 1.2691x; 1.2691x over previous
//
#include <hip/hip_runtime.h>
#include <stdint.h>

#define B_ 8
#define N_ 2048
#define D_ 128
#define KS_ 4
#define KT_ 8  // k-tiles of 64 per block: (N_/KS_)/64
#define PS_ ((size_t)B_ * N_ * D_)

typedef unsigned short u16;
typedef unsigned int u32;
using f32x4 = __attribute__((ext_vector_type(4))) float;
using bf16x8 = __attribute__((ext_vector_type(8))) short;
using u16x8 = __attribute__((ext_vector_type(8))) u16;

__device__ inline u16 f2bf(float x) {
  u32 u = __float_as_uint(x);
  return (u16)((u + 0x7FFFu + ((u >> 16) & 1u)) >> 16);
}
__device__ inline float bf2f(u16 h) { return __uint_as_float((u32)h << 16); }

// ---------------------------------------------------------------------------
// Prep: E[b][i][d] (fp32) -> ET[b][d][i] (bf16, linear)
// ---------------------------------------------------------------------------
__global__ __launch_bounds__(256) void prep_et_kernel(const float* __restrict__ E,
                                                      u16* __restrict__ ET) {
  __shared__ float Els[64][132];
  const int blk = blockIdx.x;
  const int b = blk >> 5;
  const int i0 = (blk & 31) * 64;
  const int t = threadIdx.x;
  const float* Eb = E + ((size_t)b * N_ + i0) * D_;
#pragma unroll
  for (int s = 0; s < 8; ++s) {
    const int r = (t >> 5) + 8 * s;
    const int c = t & 31;
    f32x4 v = *(const f32x4*)(Eb + r * D_ + c * 4);
#pragma unroll
    for (int e = 0; e < 4; ++e) Els[r][c * 4 + e] = v[e];
  }
  __syncthreads();
  u16* ETb = ET + (size_t)b * D_ * N_;
#pragma unroll
  for (int s = 0; s < 4; ++s) {
    const int d = (t >> 3) + 32 * s;
    const int g = t & 7;
    u16x8 pk;
#pragma unroll
    for (int e = 0; e < 8; ++e) pk[e] = f2bf(Els[g * 8 + e][d]);
    *(u16x8*)(ETb + (size_t)d * N_ + i0 + g * 8) = pk;
  }
}

// ---------------------------------------------------------------------------
// Main GEMM: Sp[ks][b][j][d] (bf16) = sum_{i in ks-range} C[b][i][j]*E[b][i][d]
// fused degree count. grid 1024 = 8b x 32jt x 4ks (XCD-swizzled: batch b -> XCD b)
// 2-phase pipeline: reg-prefetch next tile, raw barriers (no vmcnt drain).
// ---------------------------------------------------------------------------
__global__ __launch_bounds__(256) void gemm_kernel(const float* __restrict__ C,
                                                   const u16* __restrict__ ET,
                                                   u16* __restrict__ Sp,
                                                   int* __restrict__ deg) {
  __shared__ __align__(16) u16 Asw[64 * 64];
  __shared__ __align__(16) u16 Bsw[128 * 64];
  const int phys = blockIdx.x;
  const int orig = (phys & 7) * 128 + (phys >> 3);  // XCD-contiguous chunks
  const int b = orig >> 7;                          // one batch per XCD
  const int ks = (orig >> 5) & 3;
  const int jt = orig & 31;
  const int j0 = jt * 64;
  const int t = threadIdx.x;
  const int lane = t & 63;
  const int wave = t >> 6;
  const int wm = wave >> 1, wn = wave & 1;
  const int lm = lane & 15, lh = lane >> 4;

  const float* Cb = C + (size_t)b * N_ * N_;
  const u16* ETb = ET + (size_t)b * D_ * N_;
  u16* Sb = Sp + (size_t)ks * PS_ + ((size_t)b * N_ + j0) * D_;
  int* degb = deg + b * N_;

  f32x4 acc[2][4];
#pragma unroll
  for (int i = 0; i < 2; ++i)
#pragma unroll
    for (int j = 0; j < 4; ++j) acc[i][j] = (f32x4)0.0f;

  const int aRow = t >> 4, aCol = t & 15;
  const int bG = t & 7;
  const int kbase = ks * (N_ / KS_);

  // prologue: loads for tile 0
  f32x4 av[4];
  u16x8 bv[4];
#pragma unroll
  for (int s = 0; s < 4; ++s)
    av[s] = *(const f32x4*)(Cb + (size_t)(kbase + aRow + 16 * s) * N_ + j0 + aCol * 4);
#pragma unroll
  for (int s = 0; s < 4; ++s) {
    const int d = (t >> 3) + 32 * s;
    bv[s] = *(const u16x8*)(ETb + (size_t)d * N_ + kbase + bG * 8);
  }

#pragma unroll
  for (int kt = 0; kt < KT_; ++kt) {
    const int i0 = kbase + kt * 64;
    // ---- consume regs -> LDS (swizzled) + degree
#pragma unroll
    for (int s = 0; s < 4; ++s) {
      const int d = (t >> 3) + 32 * s;
      const int swz = (d ^ (d >> 3)) & 7;
      *(u16x8*)&Bsw[d * 64 + ((bG ^ swz) << 3)] = bv[s];
    }
#pragma unroll
    for (int s = 0; s < 4; ++s) {
      const int i = aRow + 16 * s;
      f32x4 v = av[s];
      int cnt = (v[0] != 0.0f) + (v[1] != 0.0f) + (v[2] != 0.0f) + (v[3] != 0.0f);
      cnt += __shfl_xor(cnt, 1);
      cnt += __shfl_xor(cnt, 2);
      cnt += __shfl_xor(cnt, 4);
      cnt += __shfl_xor(cnt, 8);
      if ((lane & 15) == 0) atomicAdd(&degb[i0 + i], cnt);
#pragma unroll
      for (int e = 0; e < 4; ++e) {
        const int jl = aCol * 4 + e;
        const int swz = (jl ^ (jl >> 3)) & 7;
        Asw[jl * 64 + (i ^ (swz << 3))] = f2bf(v[e]);
      }
    }
    // ---- prefetch next tile into regs; loads stay in flight across barrier
    if (kt + 1 < KT_) {
      const int i0n = i0 + 64;
#pragma unroll
      for (int s = 0; s < 4; ++s)
        av[s] = *(const f32x4*)(Cb + (size_t)(i0n + aRow + 16 * s) * N_ + j0 + aCol * 4);
#pragma unroll
      for (int s = 0; s < 4; ++s) {
        const int d = (t >> 3) + 32 * s;
        bv[s] = *(const u16x8*)(ETb + (size_t)d * N_ + i0n + bG * 8);
      }
    }
    // raw barrier: wait own LDS writes only (NOT vmcnt -> prefetch survives)
    asm volatile("s_waitcnt lgkmcnt(0)" ::: "memory");
    __builtin_amdgcn_sched_barrier(0);
    __builtin_amdgcn_s_barrier();
    __builtin_amdgcn_sched_barrier(0);
    // ---- fragments + MFMA (compiler inserts lgkmcnt for frag reads)
    bf16x8 af[2][2], bfr[4][2];
#pragma unroll
    for (int fm = 0; fm < 2; ++fm) {
      const int jl = wm * 32 + fm * 16 + lm;
      const int swz = (jl ^ (jl >> 3)) & 7;
#pragma unroll
      for (int kf = 0; kf < 2; ++kf) {
        const int K8 = kf * 32 + lh * 8;
        af[fm][kf] = *(const bf16x8*)&Asw[jl * 64 + (K8 ^ (swz << 3))];
      }
    }
#pragma unroll
    for (int fn = 0; fn < 4; ++fn) {
      const int nl = wn * 64 + fn * 16 + lm;
      const int swz = (nl ^ (nl >> 3)) & 7;
#pragma unroll
      for (int kf = 0; kf < 2; ++kf) {
        const int K8 = kf * 32 + lh * 8;
        bfr[fn][kf] = *(const bf16x8*)&Bsw[nl * 64 + (K8 ^ (swz << 3))];
      }
    }
#pragma unroll
    for (int kf = 0; kf < 2; ++kf)
#pragma unroll
      for (int fm = 0; fm < 2; ++fm)
#pragma unroll
        for (int fn = 0; fn < 4; ++fn)
          acc[fm][fn] = __builtin_amdgcn_mfma_f32_16x16x32_bf16(
              af[fm][kf], bfr[fn][kf], acc[fm][fn], 0, 0, 0);
    __builtin_amdgcn_sched_barrier(0);
    __builtin_amdgcn_s_barrier();
    __builtin_amdgcn_sched_barrier(0);
  }
  // ---- store partial S as bf16
#pragma unroll
  for (int fm = 0; fm < 2; ++fm)
#pragma unroll
    for (int fn = 0; fn < 4; ++fn)
#pragma unroll
      for (int r = 0; r < 4; ++r) {
        const int row = wm * 32 + fm * 16 + lh * 4 + r;
        const int col = wn * 64 + fn * 16 + lm;
        Sb[(size_t)row * D_ + col] = f2bf(acc[fm][fn][r]);
      }
}

// ---------------------------------------------------------------------------
// Output GEMM (MFMA): out[row][d] = relu( sum_f A[row][f]*W[d][f] + b[d] )
// A = [E | (sum_ks Sp)/deg], both halves k-contiguous (no transpose).
// grid 512 x 256 thr; LDS: W 64KB + A 16KB = 80KB -> 2 blocks/CU.
// ---------------------------------------------------------------------------
__global__ __launch_bounds__(256) void out_kernel(const float* __restrict__ E,
                                                  const u16* __restrict__ Sp,
                                                  const int* __restrict__ deg,
                                                  const float* __restrict__ W,
                                                  const float* __restrict__ bias,
                                                  float* __restrict__ out) {
  __shared__ __align__(16) u16 Wls[128 * 256];
  __shared__ __align__(16) u16 Als[32 * 256];
  const int r0 = blockIdx.x * 32;
  const int t = threadIdx.x;
  const int lane = t & 63;
  const int wave = t >> 6;
  const int lm = lane & 15, lh = lane >> 4;

  // ---- stage W[d][f] -> bf16 swizzled [d][k8^swz]
  {
    const int d = t >> 1;
    const int swz = (d ^ (d >> 3)) & 7;
    const float* Wd = W + d * 256 + (t & 1) * 128;
    const int k8base = (t & 1) * 16;
#pragma unroll
    for (int s = 0; s < 16; ++s) {
      f32x4 v0 = *(const f32x4*)(Wd + s * 8);
      f32x4 v1 = *(const f32x4*)(Wd + s * 8 + 4);
      u16x8 pk;
#pragma unroll
      for (int e = 0; e < 4; ++e) { pk[e] = f2bf(v0[e]); pk[4 + e] = f2bf(v1[e]); }
      *(u16x8*)&Wls[d * 256 + (((k8base + s) ^ swz) << 3)] = pk;
    }
  }
  // ---- stage A rows: E half (k8 0..15) and S/deg half (k8 16..31)
  {
    const int r = t >> 3;
    const int g = t & 7;
    const int swz = (r ^ (r >> 3)) & 7;
    const float idg = 1.0f / (float)deg[r0 + r];
    const float* Er = E + (size_t)(r0 + r) * D_;
#pragma unroll
    for (int h = 0; h < 2; ++h) {
      const int k8 = g + 8 * h;
      f32x4 v0 = *(const f32x4*)(Er + k8 * 8);
      f32x4 v1 = *(const f32x4*)(Er + k8 * 8 + 4);
      u16x8 pk;
#pragma unroll
      for (int e = 0; e < 4; ++e) { pk[e] = f2bf(v0[e]); pk[4 + e] = f2bf(v1[e]); }
      *(u16x8*)&Als[r * 256 + ((k8 ^ swz) << 3)] = pk;
    }
    const size_t off = (size_t)(r0 + r) * D_;
#pragma unroll
    for (int h = 0; h < 2; ++h) {
      const int kq = g + 8 * h;
      u16x8 p0 = *(const u16x8*)(Sp + 0 * PS_ + off + kq * 8);
      u16x8 p1 = *(const u16x8*)(Sp + 1 * PS_ + off + kq * 8);
      u16x8 p2 = *(const u16x8*)(Sp + 2 * PS_ + off + kq * 8);
      u16x8 p3 = *(const u16x8*)(Sp + 3 * PS_ + off + kq * 8);
      u16x8 pk;
#pragma unroll
      for (int e = 0; e < 8; ++e) {
        float s = (bf2f(p0[e]) + bf2f(p1[e])) + (bf2f(p2[e]) + bf2f(p3[e]));
        pk[e] = f2bf(s * idg);
      }
      const int k8 = 16 + kq;
      *(u16x8*)&Als[r * 256 + ((k8 ^ swz) << 3)] = pk;
    }
  }
  __syncthreads();
  // ---- MFMA: wave -> 32 d-columns; 2m x 2n frags; K=256
  f32x4 acc[2][2];
#pragma unroll
  for (int i = 0; i < 2; ++i)
#pragma unroll
    for (int j = 0; j < 2; ++j) acc[i][j] = (f32x4)0.0f;
  const int dbase = wave * 32;
#pragma unroll
  for (int kf = 0; kf < 8; ++kf) {
    bf16x8 af[2], bfr[2];
#pragma unroll
    for (int fm = 0; fm < 2; ++fm) {
      const int r = fm * 16 + lm;
      const int swz = (r ^ (r >> 3)) & 7;
      af[fm] = *(const bf16x8*)&Als[r * 256 + (((kf * 4 + lh) ^ swz) << 3)];
    }
#pragma unroll
    for (int fn = 0; fn < 2; ++fn) {
      const int d = dbase + fn * 16 + lm;
      const int swz = (d ^ (d >> 3)) & 7;
      bfr[fn] = *(const bf16x8*)&Wls[d * 256 + (((kf * 4 + lh) ^ swz) << 3)];
    }
#pragma unroll
    for (int fm = 0; fm < 2; ++fm)
#pragma unroll
      for (int fn = 0; fn < 2; ++fn)
        acc[fm][fn] = __builtin_amdgcn_mfma_f32_16x16x32_bf16(af[fm], bfr[fn],
                                                              acc[fm][fn], 0, 0, 0);
  }
  // ---- epilogue: bias + relu
  float bb[2] = {bias[dbase + lm], bias[dbase + 16 + lm]};
#pragma unroll
  for (int fm = 0; fm < 2; ++fm)
#pragma unroll
    for (int fn = 0; fn < 2; ++fn)
#pragma unroll
      for (int r = 0; r < 4; ++r) {
        const int row = r0 + fm * 16 + lh * 4 + r;
        const int d = dbase + fn * 16 + lm;
        float x = acc[fm][fn][r] + bb[fn];
        out[(size_t)row * D_ + d] = x > 0.0f ? x : 0.0f;
      }
}

extern "C" void kernel_launch(void* const* d_in, const int* in_sizes, int n_in,
                              void* d_out, int out_size, void* d_ws, size_t ws_size,
                              hipStream_t stream) {
  (void)in_sizes; (void)n_in; (void)out_size; (void)ws_size;
  const float* E = (const float*)d_in[0];
  const float* C = (const float*)d_in[1];
  const float* W = (const float*)d_in[2];
  const float* bias = (const float*)d_in[3];
  float* out = (float*)d_out;

  // ws: deg int[8*2048] | ET bf16[8][128][2048] | Sp bf16[4][8*2048][128]  (~21MB)
  int* deg = (int*)d_ws;
  u16* ET = (u16*)((char*)d_ws + 65536);
  u16* Sp = (u16*)((char*)d_ws + 65536 + 4194304);

  hipMemsetAsync(deg, 0, B_ * N_ * sizeof(int), stream);
  hipLaunchKernelGGL(prep_et_kernel, dim3(256), dim3(256), 0, stream, E, ET);
  hipLaunchKernelGGL(gemm_kernel, dim3(1024), dim3(256), 0, stream, C, ET, Sp, deg);
  hipLaunchKernelGGL(out_kernel, dim3(512), dim3(256), 0, stream, E, Sp, deg, W, bias, out);
}

// Round 3
// 229.006 us; speedup vs baseline: 1.2782x; 1.0071x over previous
//
#include <hip/hip_runtime.h>
#include <stdint.h>

#define B_ 8
#define N_ 2048
#define D_ 128
#define NT_ 32            // 64-wide k-tiles per batch
#define KT_ 16            // tiles per gemm block (ksplit = 2)
#define TILE_BYTES 16384  // ET tile image: 128 d x 64 k x 2B
#define PS_ ((size_t)B_ * N_ * D_)

typedef unsigned short u16;
typedef unsigned int u32;
using f32x4 = __attribute__((ext_vector_type(4))) float;
using bf16x8 = __attribute__((ext_vector_type(8))) short;
using u16x8 = __attribute__((ext_vector_type(8))) u16;

__device__ inline u16 f2bf(float x) {
  u32 u = __float_as_uint(x);
  return (u16)((u + 0x7FFFu + ((u >> 16) & 1u)) >> 16);
}
__device__ inline float bf2f(u16 h) { return __uint_as_float((u32)h << 16); }

__device__ inline void glds16(const void* g, void* l) {
  __builtin_amdgcn_global_load_lds((const __attribute__((address_space(1))) void*)g,
                                   (__attribute__((address_space(3))) void*)l, 16, 0, 0);
}

// ---------------------------------------------------------------------------
// Prep: E[b][k][d] fp32 -> ETsw[b][tile][16KB image], image = exact LDS bytes
// the gemm wants: elem(d, klocal) at d*64 + (((klocal>>3)^swz(d))<<3)+(klocal&7)
// ---------------------------------------------------------------------------
__global__ __launch_bounds__(256) void prep_et_kernel(const float* __restrict__ E,
                                                      u16* __restrict__ ETsw) {
  __shared__ float Els[64][132];
  const int blk = blockIdx.x;
  const int b = blk >> 5;
  const int g = blk & 31;  // k-tile
  const int t = threadIdx.x;
  const float* Eb = E + ((size_t)b * N_ + g * 64) * D_;
#pragma unroll
  for (int s = 0; s < 8; ++s) {
    const int f4 = t + 256 * s;
    const int r = f4 >> 5;
    const int c4 = f4 & 31;
    f32x4 v = *(const f32x4*)(Eb + (size_t)r * D_ + c4 * 4);
#pragma unroll
    for (int e = 0; e < 4; ++e) Els[r][c4 * 4 + e] = v[e];
  }
  __syncthreads();
  u16* img = ETsw + ((size_t)b * NT_ + g) * (TILE_BYTES / 2);
  const int d = t >> 1;
  const int swz = (d ^ (d >> 3)) & 7;
#pragma unroll
  for (int gg = 0; gg < 4; ++gg) {
    const int grp = (t & 1) * 4 + gg;
    u16x8 pk;
#pragma unroll
    for (int e = 0; e < 8; ++e) pk[e] = f2bf(Els[grp * 8 + e][d]);
    *(u16x8*)(img + d * 64 + ((grp ^ swz) << 3)) = pk;
  }
}

// W[d][f] fp32 -> Wsw 64KB bf16 image (swizzled [d][k8^swz]) for glds staging
__global__ __launch_bounds__(256) void prep_w_kernel(const float* __restrict__ W,
                                                     u16* __restrict__ Wsw) {
  const int t = threadIdx.x;
  const int d = t >> 1;
  const int swz = (d ^ (d >> 3)) & 7;
#pragma unroll
  for (int s = 0; s < 16; ++s) {
    const int k8 = (t & 1) * 16 + s;
    f32x4 v0 = *(const f32x4*)(W + d * 256 + k8 * 8);
    f32x4 v1 = *(const f32x4*)(W + d * 256 + k8 * 8 + 4);
    u16x8 pk;
#pragma unroll
    for (int e = 0; e < 4; ++e) { pk[e] = f2bf(v0[e]); pk[4 + e] = f2bf(v1[e]); }
    *(u16x8*)(Wsw + d * 256 + ((k8 ^ swz) << 3)) = pk;
  }
}

// ---------------------------------------------------------------------------
// Main GEMM: Sp[ks][row][d] = sum_{k in half} C[b][k][j]*E[b][k][d], bf16 out.
// 512 blocks = 8b x 32jt x 2ks (batch->XCD), 256 thr. Counted-vmcnt pipeline:
// glds B(kt+1) early; MFMA(cur); consume A-regs->LDS[nxt] (auto vmcnt(4));
// issue A(kt+2); vmcnt(8) drains only glds before the single barrier.
// ---------------------------------------------------------------------------
__global__ __launch_bounds__(256) void gemm_kernel(const float* __restrict__ C,
                                                   const u16* __restrict__ ETsw,
                                                   u16* __restrict__ Sp,
                                                   int* __restrict__ deg) {
  __shared__ __align__(16) u16 Asw[2][64 * 64];   // 16KB
  __shared__ __align__(16) u16 Bsw[2][128 * 64];  // 32KB
  const int phys = blockIdx.x;
  const int orig = (phys & 7) * 64 + (phys >> 3);  // 64 blocks per XCD = 1 batch
  const int b = orig >> 6;
  const int ks = (orig >> 5) & 1;
  const int jt = orig & 31;
  const int j0 = jt * 64;
  const int t = threadIdx.x;
  const int lane = t & 63;
  const int wave = t >> 6;
  const int wm = wave >> 1, wn = wave & 1;
  const int lm = lane & 15, lh = lane >> 4;
  const int aRow = t >> 4, aCol = t & 15;

  const float* Cb = C + (size_t)b * N_ * N_;
  const char* Eimg = (const char*)(ETsw + (size_t)b * NT_ * (TILE_BYTES / 2));
  int* degb = deg + b * N_;
  const int g0 = ks * KT_;

  f32x4 acc[2][4];
#pragma unroll
  for (int i = 0; i < 2; ++i)
#pragma unroll
    for (int j = 0; j < 4; ++j) acc[i][j] = (f32x4)0.0f;
  f32x4 av[4];

#define ISSUE_B(gi, buf)                                                          \
  {                                                                               \
    _Pragma("unroll") for (int s = 0; s < 4; ++s) {                               \
      const int chunk = s * 4 + wave;                                             \
      glds16(Eimg + (size_t)(gi)*TILE_BYTES + chunk * 1024 + lane * 16,           \
             (char*)&Bsw[buf][0] + chunk * 1024);                                 \
    }                                                                             \
  }
#define LOAD_A(gi)                                                                \
  {                                                                               \
    _Pragma("unroll") for (int s = 0; s < 4; ++s) av[s] =                         \
        *(const f32x4*)(Cb + (size_t)((gi)*64 + aRow + 16 * s) * N_ + j0 + aCol * 4); \
  }
#define WRITE_A(gi, buf)                                                          \
  {                                                                               \
    _Pragma("unroll") for (int s = 0; s < 4; ++s) {                               \
      const int i = aRow + 16 * s;                                                \
      f32x4 v = av[s];                                                            \
      int cnt = (v[0] != 0.0f) + (v[1] != 0.0f) + (v[2] != 0.0f) + (v[3] != 0.0f);\
      cnt += __shfl_xor(cnt, 1);                                                  \
      cnt += __shfl_xor(cnt, 2);                                                  \
      cnt += __shfl_xor(cnt, 4);                                                  \
      cnt += __shfl_xor(cnt, 8);                                                  \
      if ((lane & 15) == 0) atomicAdd(&degb[(gi)*64 + i], cnt);                   \
      _Pragma("unroll") for (int e = 0; e < 4; ++e) {                             \
        const int jl = aCol * 4 + e;                                              \
        const int sz = (jl ^ (jl >> 3)) & 7;                                      \
        Asw[buf][jl * 64 + (i ^ (sz << 3))] = f2bf(v[e]);                         \
      }                                                                           \
    }                                                                             \
  }
#define MFMA_PHASE(buf)                                                           \
  {                                                                               \
    bf16x8 af[2][2], bfr[4][2];                                                   \
    _Pragma("unroll") for (int fm = 0; fm < 2; ++fm) {                            \
      const int jl = wm * 32 + fm * 16 + lm;                                      \
      const int sz = (jl ^ (jl >> 3)) & 7;                                        \
      _Pragma("unroll") for (int kf = 0; kf < 2; ++kf) {                          \
        const int K8 = kf * 32 + lh * 8;                                          \
        af[fm][kf] = *(const bf16x8*)&Asw[buf][jl * 64 + (K8 ^ (sz << 3))];       \
      }                                                                           \
    }                                                                             \
    _Pragma("unroll") for (int fn = 0; fn < 4; ++fn) {                            \
      const int nl = wn * 64 + fn * 16 + lm;                                      \
      const int sz = (nl ^ (nl >> 3)) & 7;                                        \
      _Pragma("unroll") for (int kf = 0; kf < 2; ++kf) {                          \
        const int K8 = kf * 32 + lh * 8;                                          \
        bfr[fn][kf] = *(const bf16x8*)&Bsw[buf][nl * 64 + (K8 ^ (sz << 3))];      \
      }                                                                           \
    }                                                                             \
    _Pragma("unroll") for (int kf = 0; kf < 2; ++kf)                              \
        _Pragma("unroll") for (int fm = 0; fm < 2; ++fm)                          \
        _Pragma("unroll") for (int fn = 0; fn < 4; ++fn) acc[fm][fn] =            \
        __builtin_amdgcn_mfma_f32_16x16x32_bf16(af[fm][kf], bfr[fn][kf],          \
                                                acc[fm][fn], 0, 0, 0);            \
  }

  // ---- prologue: tile 0 staged, tile-1 A-loads in flight
  ISSUE_B(g0, 0);
  LOAD_A(g0);
  WRITE_A(g0, 0);  // av read forces vmcnt(0): B0 + av0 drained
  LOAD_A(g0 + 1);
  asm volatile("s_waitcnt lgkmcnt(0)" ::: "memory");
  __builtin_amdgcn_sched_barrier(0);
  __builtin_amdgcn_s_barrier();
  __builtin_amdgcn_sched_barrier(0);

  int cur = 0;
  for (int kt = 0; kt < KT_ - 1; ++kt) {
    ISSUE_B(g0 + kt + 1, cur ^ 1);
    __builtin_amdgcn_sched_barrier(0);
    MFMA_PHASE(cur);
    __builtin_amdgcn_sched_barrier(0);
    WRITE_A(g0 + kt + 1, cur ^ 1);  // auto vmcnt(4): drains old atomics + av
    __builtin_amdgcn_sched_barrier(0);
    if (kt < KT_ - 2) LOAD_A(g0 + kt + 2);
    __builtin_amdgcn_sched_barrier(0);
    asm volatile("s_waitcnt vmcnt(8)" ::: "memory");  // drain B(kt+1) glds only
    asm volatile("s_waitcnt lgkmcnt(0)" ::: "memory");
    __builtin_amdgcn_sched_barrier(0);
    __builtin_amdgcn_s_barrier();
    __builtin_amdgcn_sched_barrier(0);
    cur ^= 1;
  }
  MFMA_PHASE(cur);

  u16* Sb = Sp + (size_t)ks * PS_ + ((size_t)b * N_ + j0) * D_;
#pragma unroll
  for (int fm = 0; fm < 2; ++fm)
#pragma unroll
    for (int fn = 0; fn < 4; ++fn)
#pragma unroll
      for (int r = 0; r < 4; ++r) {
        const int row = wm * 32 + fm * 16 + lh * 4 + r;
        const int col = wn * 64 + fn * 16 + lm;
        Sb[(size_t)row * D_ + col] = f2bf(acc[fm][fn][r]);
      }
#undef ISSUE_B
#undef LOAD_A
#undef WRITE_A
#undef MFMA_PHASE
}

// ---------------------------------------------------------------------------
// Output GEMM: out[row][d] = relu(sum_f A[row][f]*W[d][f] + b[d]),
// A = [E | (Sp0+Sp1)/deg]. W staged via glds from pre-swizzled image.
// 512 blocks x 256 thr, 80KB LDS -> 2 blocks/CU, one barrier.
// ---------------------------------------------------------------------------
__global__ __launch_bounds__(256) void out_kernel(const float* __restrict__ E,
                                                  const u16* __restrict__ Sp,
                                                  const int* __restrict__ deg,
                                                  const u16* __restrict__ Wsw,
                                                  const float* __restrict__ bias,
                                                  float* __restrict__ out) {
  __shared__ __align__(16) u16 Wls[128 * 256];
  __shared__ __align__(16) u16 Als[32 * 256];
  const int r0 = blockIdx.x * 32;
  const int t = threadIdx.x;
  const int lane = t & 63;
  const int wave = t >> 6;
  const int lm = lane & 15, lh = lane >> 4;

  // stage W: 64 x 1KB chunks, straight byte copy (image pre-swizzled)
#pragma unroll
  for (int s = 0; s < 16; ++s) {
    const int chunk = s * 4 + wave;
    glds16((const char*)Wsw + chunk * 1024 + lane * 16, (char*)Wls + chunk * 1024);
  }
  // stage A rows (reg path): E half k8=0..15, (Sp0+Sp1)/deg half k8=16..31
  const int r = t >> 3, gq = t & 7;
  const int swzr = (r ^ (r >> 3)) & 7;
  const float idg = 1.0f / (float)deg[r0 + r];
  const float* Er = E + (size_t)(r0 + r) * D_;
#pragma unroll
  for (int h = 0; h < 2; ++h) {
    const int k8 = gq + 8 * h;
    f32x4 v0 = *(const f32x4*)(Er + k8 * 8);
    f32x4 v1 = *(const f32x4*)(Er + k8 * 8 + 4);
    u16x8 pk;
#pragma unroll
    for (int e = 0; e < 4; ++e) { pk[e] = f2bf(v0[e]); pk[4 + e] = f2bf(v1[e]); }
    *(u16x8*)&Als[r * 256 + ((k8 ^ swzr) << 3)] = pk;
  }
  const size_t off = (size_t)(r0 + r) * D_;
#pragma unroll
  for (int h = 0; h < 2; ++h) {
    const int kq = gq + 8 * h;
    u16x8 p0 = *(const u16x8*)(Sp + off + kq * 8);
    u16x8 p1 = *(const u16x8*)(Sp + PS_ + off + kq * 8);
    u16x8 pk;
#pragma unroll
    for (int e = 0; e < 8; ++e) pk[e] = f2bf((bf2f(p0[e]) + bf2f(p1[e])) * idg);
    *(u16x8*)&Als[r * 256 + (((16 + kq) ^ swzr) << 3)] = pk;
  }
  __syncthreads();  // drains glds (vmcnt) + ds writes (lgkm)

  f32x4 acc[2][2];
#pragma unroll
  for (int i = 0; i < 2; ++i)
#pragma unroll
    for (int j = 0; j < 2; ++j) acc[i][j] = (f32x4)0.0f;
  const int dbase = wave * 32;
#pragma unroll
  for (int kf = 0; kf < 8; ++kf) {
    bf16x8 af[2], bfr[2];
#pragma unroll
    for (int fm = 0; fm < 2; ++fm) {
      const int rr = fm * 16 + lm;
      const int sz = (rr ^ (rr >> 3)) & 7;
      af[fm] = *(const bf16x8*)&Als[rr * 256 + (((kf * 4 + lh) ^ sz) << 3)];
    }
#pragma unroll
    for (int fn = 0; fn < 2; ++fn) {
      const int d = dbase + fn * 16 + lm;
      const int sz = (d ^ (d >> 3)) & 7;
      bfr[fn] = *(const bf16x8*)&Wls[d * 256 + (((kf * 4 + lh) ^ sz) << 3)];
    }
#pragma unroll
    for (int fm = 0; fm < 2; ++fm)
#pragma unroll
      for (int fn = 0; fn < 2; ++fn)
        acc[fm][fn] = __builtin_amdgcn_mfma_f32_16x16x32_bf16(af[fm], bfr[fn],
                                                              acc[fm][fn], 0, 0, 0);
  }
  float bb[2] = {bias[dbase + lm], bias[dbase + 16 + lm]};
#pragma unroll
  for (int fm = 0; fm < 2; ++fm)
#pragma unroll
    for (int fn = 0; fn < 2; ++fn)
#pragma unroll
      for (int rr = 0; rr < 4; ++rr) {
        const int row = r0 + fm * 16 + lh * 4 + rr;
        const int d = dbase + fn * 16 + lm;
        float x = acc[fm][fn][rr] + bb[fn];
        out[(size_t)row * D_ + d] = x > 0.0f ? x : 0.0f;
      }
}

extern "C" void kernel_launch(void* const* d_in, const int* in_sizes, int n_in,
                              void* d_out, int out_size, void* d_ws, size_t ws_size,
                              hipStream_t stream) {
  (void)in_sizes; (void)n_in; (void)out_size; (void)ws_size;
  const float* E = (const float*)d_in[0];
  const float* C = (const float*)d_in[1];
  const float* W = (const float*)d_in[2];
  const float* bias = (const float*)d_in[3];
  float* out = (float*)d_out;

  // ws: deg int[16K] | ETsw 4MB | Wsw 64KB | Sp bf16[2][B*N][D] (8.4MB)
  char* ws = (char*)d_ws;
  int* deg = (int*)ws;
  u16* ETsw = (u16*)(ws + 65536);
  u16* Wsw = (u16*)(ws + 65536 + 4194304);
  u16* Sp = (u16*)(ws + 65536 + 4194304 + 65536);

  hipMemsetAsync(deg, 0, B_ * N_ * sizeof(int), stream);
  hipLaunchKernelGGL(prep_et_kernel, dim3(256), dim3(256), 0, stream, E, ETsw);
  hipLaunchKernelGGL(prep_w_kernel, dim3(1), dim3(256), 0, stream, W, Wsw);
  hipLaunchKernelGGL(gemm_kernel, dim3(512), dim3(256), 0, stream, C, ETsw, Sp, deg);
  hipLaunchKernelGGL(out_kernel, dim3(512), dim3(256), 0, stream, E, Sp, deg, Wsw, bias, out);
}

// Round 5
// 221.807 us; speedup vs baseline: 1.3196x; 1.0325x over previous
//
#include <hip/hip_runtime.h>
#include <stdint.h>

#define B_ 8
#define N_ 2048
#define D_ 128
#define NT_ 32            // 64-wide k-tiles per batch
#define KT_ 16            // tiles per gemm block (ksplit = 2)
#define TILE_BYTES 16384  // ET tile image: 128 d x 64 k x 2B
#define PS_ ((size_t)B_ * N_ * D_)

typedef unsigned short u16;
typedef unsigned int u32;
using f32x4 = __attribute__((ext_vector_type(4))) float;
using bf16x8 = __attribute__((ext_vector_type(8))) short;
using u16x8 = __attribute__((ext_vector_type(8))) u16;

__device__ inline u16 f2bf(float x) {
  u32 u = __float_as_uint(x);
  return (u16)((u + 0x7FFFu + ((u >> 16) & 1u)) >> 16);
}
__device__ inline float bf2f(u16 h) { return __uint_as_float((u32)h << 16); }

__device__ inline void glds16(const void* g, void* l) {
  __builtin_amdgcn_global_load_lds((const __attribute__((address_space(1))) void*)g,
                                   (__attribute__((address_space(3))) void*)l, 16, 0, 0);
}

// ---------------------------------------------------------------------------
// Prep (257 blocks): 0..255 -> ET tile images; 256 -> W bf16 swizzled image.
// ET image = exact LDS bytes gemm stages via glds.
// ---------------------------------------------------------------------------
__global__ __launch_bounds__(256) void prep_kernel(const float* __restrict__ E,
                                                   const float* __restrict__ W,
                                                   u16* __restrict__ ETsw,
                                                   u16* __restrict__ Wsw) {
  const int blk = blockIdx.x;
  const int t = threadIdx.x;
  if (blk == 256) {  // W[d][f] -> Wsw swizzled [d][k8^swz]
    const int d = t >> 1;
    const int swz = (d ^ (d >> 3)) & 7;
#pragma unroll
    for (int s = 0; s < 16; ++s) {
      const int k8 = (t & 1) * 16 + s;
      f32x4 v0 = *(const f32x4*)(W + d * 256 + k8 * 8);
      f32x4 v1 = *(const f32x4*)(W + d * 256 + k8 * 8 + 4);
      u16x8 pk;
#pragma unroll
      for (int e = 0; e < 4; ++e) { pk[e] = f2bf(v0[e]); pk[4 + e] = f2bf(v1[e]); }
      *(u16x8*)(Wsw + d * 256 + ((k8 ^ swz) << 3)) = pk;
    }
    return;
  }
  __shared__ float Els[64][132];
  const int b = blk >> 5;
  const int g = blk & 31;  // k-tile
  const float* Eb = E + ((size_t)b * N_ + g * 64) * D_;
#pragma unroll
  for (int s = 0; s < 8; ++s) {
    const int f4 = t + 256 * s;
    const int r = f4 >> 5;
    const int c4 = f4 & 31;
    f32x4 v = *(const f32x4*)(Eb + (size_t)r * D_ + c4 * 4);
#pragma unroll
    for (int e = 0; e < 4; ++e) Els[r][c4 * 4 + e] = v[e];
  }
  __syncthreads();
  u16* img = ETsw + ((size_t)b * NT_ + g) * (TILE_BYTES / 2);
  const int d = t >> 1;
  const int swz = (d ^ (d >> 3)) & 7;
#pragma unroll
  for (int gg = 0; gg < 4; ++gg) {
    const int grp = (t & 1) * 4 + gg;
    u16x8 pk;
#pragma unroll
    for (int e = 0; e < 8; ++e) pk[e] = f2bf(Els[grp * 8 + e][d]);
    *(u16x8*)(img + d * 64 + ((grp ^ swz) << 3)) = pk;
  }
}

// ---------------------------------------------------------------------------
// Main GEMM: Sp[ks][row][d] = sum_{k in half} C[b][k][j]*E[b][k][d], bf16 out.
// 512 blocks = 8b x 32jt x 2ks (batch->XCD), 256 thr, 48KB LDS (3 blocks/CU).
// NO atomics/shfl in hot loop: zero-count via __any (rare path only).
// Counted vmcnt(4) steady state; peeled last iteration drains vmcnt(0).
// ---------------------------------------------------------------------------
__global__ __launch_bounds__(256) void gemm_kernel(const float* __restrict__ C,
                                                   const u16* __restrict__ ETsw,
                                                   u16* __restrict__ Sp,
                                                   int* __restrict__ zeros) {
  __shared__ __align__(16) u16 Asw[2][64 * 64];   // 16KB
  __shared__ __align__(16) u16 Bsw[2][128 * 64];  // 32KB
  const int phys = blockIdx.x;
  const int orig = (phys & 7) * 64 + (phys >> 3);  // 64 blocks per XCD = 1 batch
  const int b = orig >> 6;
  const int ks = (orig >> 5) & 1;
  const int jt = orig & 31;
  const int j0 = jt * 64;
  const int t = threadIdx.x;
  const int lane = t & 63;
  const int wave = t >> 6;
  const int wm = wave >> 1, wn = wave & 1;
  const int lm = lane & 15, lh = lane >> 4;
  const int aRow = t >> 4, aCol = t & 15;

  const float* Cb = C + (size_t)b * N_ * N_;
  const char* Eimg = (const char*)(ETsw + (size_t)b * NT_ * (TILE_BYTES / 2));
  int* zb = zeros + b * N_;
  const int g0 = ks * KT_;

  f32x4 acc[2][4];
#pragma unroll
  for (int i = 0; i < 2; ++i)
#pragma unroll
    for (int j = 0; j < 4; ++j) acc[i][j] = (f32x4)0.0f;
  f32x4 av[4];

#define ISSUE_B(gi, buf)                                                          \
  {                                                                               \
    _Pragma("unroll") for (int s = 0; s < 4; ++s) {                               \
      const int chunk = s * 4 + wave;                                             \
      glds16(Eimg + (size_t)(gi)*TILE_BYTES + chunk * 1024 + lane * 16,           \
             (char*)&Bsw[buf][0] + chunk * 1024);                                 \
    }                                                                             \
  }
#define LOAD_A(gi)                                                                \
  {                                                                               \
    _Pragma("unroll") for (int s = 0; s < 4; ++s) av[s] =                         \
        *(const f32x4*)(Cb + (size_t)((gi)*64 + aRow + 16 * s) * N_ + j0 + aCol * 4); \
  }
#define WRITE_A(gi, buf)                                                          \
  {                                                                               \
    _Pragma("unroll") for (int s = 0; s < 4; ++s) {                               \
      const int i = aRow + 16 * s;                                                \
      f32x4 v = av[s];                                                            \
      int zc = (v[0] == 0.0f) + (v[1] == 0.0f) + (v[2] == 0.0f) + (v[3] == 0.0f);\
      if (__any(zc)) {  /* rare: exact-zero entries in C */                       \
        if (zc) atomicAdd(&zb[(gi)*64 + i], zc);                                  \
      }                                                                           \
      _Pragma("unroll") for (int e = 0; e < 4; ++e) {                             \
        const int jl = aCol * 4 + e;                                              \
        const int sz = (jl ^ (jl >> 3)) & 7;                                      \
        Asw[buf][jl * 64 + (i ^ (sz << 3))] = f2bf(v[e]);                         \
      }                                                                           \
    }                                                                             \
  }
#define MFMA_PHASE(buf)                                                           \
  {                                                                               \
    bf16x8 af[2][2], bfr[4][2];                                                   \
    _Pragma("unroll") for (int fm = 0; fm < 2; ++fm) {                            \
      const int jl = wm * 32 + fm * 16 + lm;                                      \
      const int sz = (jl ^ (jl >> 3)) & 7;                                        \
      _Pragma("unroll") for (int kf = 0; kf < 2; ++kf) {                          \
        const int K8 = kf * 32 + lh * 8;                                          \
        af[fm][kf] = *(const bf16x8*)&Asw[buf][jl * 64 + (K8 ^ (sz << 3))];       \
      }                                                                           \
    }                                                                             \
    _Pragma("unroll") for (int fn = 0; fn < 4; ++fn) {                            \
      const int nl = wn * 64 + fn * 16 + lm;                                      \
      const int sz = (nl ^ (nl >> 3)) & 7;                                        \
      _Pragma("unroll") for (int kf = 0; kf < 2; ++kf) {                          \
        const int K8 = kf * 32 + lh * 8;                                          \
        bfr[fn][kf] = *(const bf16x8*)&Bsw[buf][nl * 64 + (K8 ^ (sz << 3))];      \
      }                                                                           \
    }                                                                             \
    _Pragma("unroll") for (int kf = 0; kf < 2; ++kf)                              \
        _Pragma("unroll") for (int fm = 0; fm < 2; ++fm)                          \
        _Pragma("unroll") for (int fn = 0; fn < 4; ++fn) acc[fm][fn] =            \
        __builtin_amdgcn_mfma_f32_16x16x32_bf16(af[fm][kf], bfr[fn][kf],          \
                                                acc[fm][fn], 0, 0, 0);            \
  }

  // ---- prologue: tile g0 staged; av(g0+1) in flight
  ISSUE_B(g0, 0);
  LOAD_A(g0);
  WRITE_A(g0, 0);  // av consume drains everything (prologue only)
  LOAD_A(g0 + 1);
  asm volatile("s_waitcnt lgkmcnt(0)" ::: "memory");
  __builtin_amdgcn_sched_barrier(0);
  __builtin_amdgcn_s_barrier();
  __builtin_amdgcn_sched_barrier(0);

  int cur = 0;
  for (int kt = 0; kt < KT_ - 2; ++kt) {  // steady state: 14 iterations
    ISSUE_B(g0 + kt + 1, cur ^ 1);
    __builtin_amdgcn_sched_barrier(0);
    MFMA_PHASE(cur);
    __builtin_amdgcn_sched_barrier(0);
    WRITE_A(g0 + kt + 1, cur ^ 1);  // av consume: auto vmcnt(4), glds stay in flight
    __builtin_amdgcn_sched_barrier(0);
    LOAD_A(g0 + kt + 2);
    __builtin_amdgcn_sched_barrier(0);
    asm volatile("s_waitcnt vmcnt(4)" ::: "memory");  // drain this tile's glds only
    asm volatile("s_waitcnt lgkmcnt(0)" ::: "memory");
    __builtin_amdgcn_sched_barrier(0);
    __builtin_amdgcn_s_barrier();
    __builtin_amdgcn_sched_barrier(0);
    cur ^= 1;
  }
  // ---- peeled iteration KT_-2: no next A-load; full drain before barrier
  ISSUE_B(g0 + KT_ - 1, cur ^ 1);
  __builtin_amdgcn_sched_barrier(0);
  MFMA_PHASE(cur);
  __builtin_amdgcn_sched_barrier(0);
  WRITE_A(g0 + KT_ - 1, cur ^ 1);
  __builtin_amdgcn_sched_barrier(0);
  asm volatile("s_waitcnt vmcnt(0)" ::: "memory");
  asm volatile("s_waitcnt lgkmcnt(0)" ::: "memory");
  __builtin_amdgcn_sched_barrier(0);
  __builtin_amdgcn_s_barrier();
  __builtin_amdgcn_sched_barrier(0);
  cur ^= 1;
  MFMA_PHASE(cur);

  u16* Sb = Sp + (size_t)ks * PS_ + ((size_t)b * N_ + j0) * D_;
#pragma unroll
  for (int fm = 0; fm < 2; ++fm)
#pragma unroll
    for (int fn = 0; fn < 4; ++fn)
#pragma unroll
      for (int r = 0; r < 4; ++r) {
        const int row = wm * 32 + fm * 16 + lh * 4 + r;
        const int col = wn * 64 + fn * 16 + lm;
        Sb[(size_t)row * D_ + col] = f2bf(acc[fm][fn][r]);
      }
#undef ISSUE_B
#undef LOAD_A
#undef WRITE_A
#undef MFMA_PHASE
}

// ---------------------------------------------------------------------------
// Output GEMM: out[row][d] = relu(sum_f A[row][f]*W[d][f] + b[d]),
// A = [E | (Sp0+Sp1)/(2048-zeros)]. W staged via glds from pre-swizzled image.
// 512 blocks x 256 thr, 80KB LDS -> 2 blocks/CU, one barrier.
// ---------------------------------------------------------------------------
__global__ __launch_bounds__(256) void out_kernel(const float* __restrict__ E,
                                                  const u16* __restrict__ Sp,
                                                  const int* __restrict__ zeros,
                                                  const u16* __restrict__ Wsw,
                                                  const float* __restrict__ bias,
                                                  float* __restrict__ out) {
  __shared__ __align__(16) u16 Wls[128 * 256];
  __shared__ __align__(16) u16 Als[32 * 256];
  const int r0 = blockIdx.x * 32;
  const int t = threadIdx.x;
  const int lane = t & 63;
  const int wave = t >> 6;
  const int lm = lane & 15, lh = lane >> 4;

  // stage W: 64 x 1KB chunks, straight byte copy (image pre-swizzled)
#pragma unroll
  for (int s = 0; s < 16; ++s) {
    const int chunk = s * 4 + wave;
    glds16((const char*)Wsw + chunk * 1024 + lane * 16, (char*)Wls + chunk * 1024);
  }
  // stage A rows: E half k8=0..15, (Sp0+Sp1)/deg half k8=16..31
  const int r = t >> 3, gq = t & 7;
  const int swzr = (r ^ (r >> 3)) & 7;
  const float idg = 1.0f / (2048.0f - (float)zeros[r0 + r]);
  const float* Er = E + (size_t)(r0 + r) * D_;
#pragma unroll
  for (int h = 0; h < 2; ++h) {
    const int k8 = gq + 8 * h;
    f32x4 v0 = *(const f32x4*)(Er + k8 * 8);
    f32x4 v1 = *(const f32x4*)(Er + k8 * 8 + 4);
    u16x8 pk;
#pragma unroll
    for (int e = 0; e < 4; ++e) { pk[e] = f2bf(v0[e]); pk[4 + e] = f2bf(v1[e]); }
    *(u16x8*)&Als[r * 256 + ((k8 ^ swzr) << 3)] = pk;
  }
  const size_t off = (size_t)(r0 + r) * D_;
#pragma unroll
  for (int h = 0; h < 2; ++h) {
    const int kq = gq + 8 * h;
    u16x8 p0 = *(const u16x8*)(Sp + off + kq * 8);
    u16x8 p1 = *(const u16x8*)(Sp + PS_ + off + kq * 8);
    u16x8 pk;
#pragma unroll
    for (int e = 0; e < 8; ++e) pk[e] = f2bf((bf2f(p0[e]) + bf2f(p1[e])) * idg);
    *(u16x8*)&Als[r * 256 + (((16 + kq) ^ swzr) << 3)] = pk;
  }
  __syncthreads();  // drains glds (vmcnt) + ds writes (lgkm)

  f32x4 acc[2][2];
#pragma unroll
  for (int i = 0; i < 2; ++i)
#pragma unroll
    for (int j = 0; j < 2; ++j) acc[i][j] = (f32x4)0.0f;
  const int dbase = wave * 32;
#pragma unroll
  for (int kf = 0; kf < 8; ++kf) {
    bf16x8 af[2], bfr[2];
#pragma unroll
    for (int fm = 0; fm < 2; ++fm) {
      const int rr = fm * 16 + lm;
      const int sz = (rr ^ (rr >> 3)) & 7;
      af[fm] = *(const bf16x8*)&Als[rr * 256 + (((kf * 4 + lh) ^ sz) << 3)];
    }
#pragma unroll
    for (int fn = 0; fn < 2; ++fn) {
      const int d = dbase + fn * 16 + lm;
      const int sz = (d ^ (d >> 3)) & 7;
      bfr[fn] = *(const bf16x8*)&Wls[d * 256 + (((kf * 4 + lh) ^ sz) << 3)];
    }
#pragma unroll
    for (int fm = 0; fm < 2; ++fm)
#pragma unroll
      for (int fn = 0; fn < 2; ++fn)
        acc[fm][fn] = __builtin_amdgcn_mfma_f32_16x16x32_bf16(af[fm], bfr[fn],
                                                              acc[fm][fn], 0, 0, 0);
  }
  float bb[2] = {bias[dbase + lm], bias[dbase + 16 + lm]};
#pragma unroll
  for (int fm = 0; fm < 2; ++fm)
#pragma unroll
    for (int fn = 0; fn < 2; ++fn)
#pragma unroll
      for (int rr = 0; rr < 4; ++rr) {
        const int row = r0 + fm * 16 + lh * 4 + rr;
        const int d = dbase + fn * 16 + lm;
        float x = acc[fm][fn][rr] + bb[fn];
        out[(size_t)row * D_ + d] = x > 0.0f ? x : 0.0f;
      }
}

extern "C" void kernel_launch(void* const* d_in, const int* in_sizes, int n_in,
                              void* d_out, int out_size, void* d_ws, size_t ws_size,
                              hipStream_t stream) {
  (void)in_sizes; (void)n_in; (void)out_size; (void)ws_size;
  const float* E = (const float*)d_in[0];
  const float* C = (const float*)d_in[1];
  const float* W = (const float*)d_in[2];
  const float* bias = (const float*)d_in[3];
  float* out = (float*)d_out;

  // ws: zeros int[16K] | ETsw 4MB | Wsw 64KB | Sp bf16[2][B*N][D] (8.4MB)
  char* ws = (char*)d_ws;
  int* zeros = (int*)ws;
  u16* ETsw = (u16*)(ws + 65536);
  u16* Wsw = (u16*)(ws + 65536 + 4194304);
  u16* Sp = (u16*)(ws + 65536 + 4194304 + 65536);

  hipMemsetAsync(zeros, 0, B_ * N_ * sizeof(int), stream);
  hipLaunchKernelGGL(prep_kernel, dim3(257), dim3(256), 0, stream, E, W, ETsw, Wsw);
  hipLaunchKernelGGL(gemm_kernel, dim3(512), dim3(256), 0, stream, C, ETsw, Sp, zeros);
  hipLaunchKernelGGL(out_kernel, dim3(512), dim3(256), 0, stream, E, Sp, zeros, Wsw, bias, out);
}